// Round 2
// baseline (580.660 us; speedup 1.0000x reference)
//
#include <hip/hip_runtime.h>
#include <math.h>

#define NFEA  64
#define NHID  32
#define NHEAD 3
#define LCAP  256   // atoms whose e-values fit in per-wave LDS; overflow path beyond
#define GPB   4     // graphs (= waves) per 256-thread block

typedef float v2f __attribute__((ext_vector_type(2)));

// Wave-local LDS sync: all prior DS writes retired (lgkmcnt==0) => any later
// read by any lane of THIS wave sees them. "memory" clobber pins compiler
// ordering of memory ops across this point. No cross-wave coupling.
__device__ __forceinline__ void wave_sync() {
  asm volatile("s_waitcnt lgkmcnt(0)" ::: "memory");
}

// Per-atom MLP: logits = SiLU(x @ W1 + b1) @ W2 + b2
// x row per-lane (float4 loads); W1/b1/W2/b2 wave-uniform -> scalar loads (K$).
__device__ __forceinline__ void mlp_logits(
    const float* __restrict__ xrow,
    const float* __restrict__ W1, const float* __restrict__ b1,
    const float* __restrict__ W2, const float* __restrict__ b2,
    float lg[NHEAD])
{
  float4 xr[16];
#pragma unroll
  for (int q = 0; q < 16; ++q) xr[q] = ((const float4*)xrow)[q];

  v2f h[16];
#pragma unroll
  for (int j = 0; j < 16; ++j) h[j] = ((const v2f*)b1)[j];

#pragma unroll
  for (int q = 0; q < 16; ++q) {
    float xs[4] = {xr[q].x, xr[q].y, xr[q].z, xr[q].w};
#pragma unroll
    for (int dd = 0; dd < 4; ++dd) {
      v2f xd2 = {xs[dd], xs[dd]};
      const v2f* wrow = ((const v2f*)W1) + (q * 4 + dd) * 16;
#pragma unroll
      for (int j = 0; j < 16; ++j)
        h[j] = __builtin_elementwise_fma(xd2, wrow[j], h[j]);
    }
  }

  float l0 = b2[0], l1 = b2[1], l2 = b2[2];
#pragma unroll
  for (int j = 0; j < 16; ++j) {
#pragma unroll
    for (int c = 0; c < 2; ++c) {
      float hj = h[j][c];
      float s = hj * __builtin_amdgcn_rcpf(1.0f + __expf(-hj));  // SiLU
      int jj = 2 * j + c;
      l0 = fmaf(s, W2[jj * 3 + 0], l0);
      l1 = fmaf(s, W2[jj * 3 + 1], l1);
      l2 = fmaf(s, W2[jj * 3 + 2], l2);
    }
  }
  lg[0] = l0; lg[1] = l1; lg[2] = l2;
}

// Segment starts from the sorted owner array.
__global__ void gar_starts(const int* __restrict__ owner, int* __restrict__ starts,
                           int n_atoms, int n_graphs)
{
  int a = blockIdx.x * blockDim.x + threadIdx.x;
  if (a >= n_atoms) return;
  int cur  = owner[a];
  int prev = (a == 0) ? -1 : owner[a - 1];
  for (int g = prev + 1; g <= cur; ++g) starts[g] = a;
  if (a == n_atoms - 1)
    for (int g = cur + 1; g <= n_graphs; ++g) starts[g] = n_atoms;
}

// 4 graphs per 256-thread block, one wave per graph, NO block barriers
// (waves fully decoupled; wave_sync() only). Phases per wave:
//  P1: lane=atom MLP -> logits to own LDS slice, running per-head max
//  P2: e = exp(lg - m) in LDS (same-lane RAW), denom partials
//  P3a: lane=feature pooling; x re-read coalesced 256B/atom, e broadcast from LDS
//  P3b: overflow (n > LCAP) recompute path — cold, correctness only
__global__ __launch_bounds__(GPB * 64, 8) void gar_main(
    const float* __restrict__ atom_feas,
    const int*   __restrict__ starts,
    const float* __restrict__ W1, const float* __restrict__ b1,
    const float* __restrict__ W2, const float* __restrict__ b2,
    float* __restrict__ out, int n_graphs)
{
  __shared__ float4 elds_all[GPB][LCAP];
  const int w = threadIdx.x >> 6;
  const int t = threadIdx.x & 63;
  const int g = blockIdx.x * GPB + w;
  if (g >= n_graphs) return;
  float4* __restrict__ elds = elds_all[w];

  const int s0 = starts[g];
  const int s1 = starts[g + 1];
  const int n  = s1 - s0;
  float* __restrict__ outg = out + (size_t)g * (NFEA * NHEAD);

  if (n <= 0) {  // empty graph: segment_sum gives zeros
    outg[t * 3 + 0] = 0.f; outg[t * 3 + 1] = 0.f; outg[t * 3 + 2] = 0.f;
    return;
  }

  const int nc = (n + 63) >> 6;
  float m0 = -INFINITY, m1 = -INFINITY, m2 = -INFINITY;

  for (int c = 0; c < nc; ++c) {
    int i = (c << 6) + t;
    bool act = i < n;
    int aa = s0 + (act ? i : (n - 1));      // clamp keeps loads valid, CF uniform
    float lg[3];
    mlp_logits(atom_feas + (size_t)aa * NFEA, W1, b1, W2, b2, lg);
    if (act) {
      m0 = fmaxf(m0, lg[0]); m1 = fmaxf(m1, lg[1]); m2 = fmaxf(m2, lg[2]);
      if (i < LCAP) elds[i] = make_float4(lg[0], lg[1], lg[2], 0.f);
    }
  }
#pragma unroll
  for (int off = 32; off > 0; off >>= 1) {
    m0 = fmaxf(m0, __shfl_xor(m0, off));
    m1 = fmaxf(m1, __shfl_xor(m1, off));
    m2 = fmaxf(m2, __shfl_xor(m2, off));
  }
  wave_sync();

  float d0 = 0.f, d1 = 0.f, d2 = 0.f;
  const int ncached = n < LCAP ? n : LCAP;
  for (int i = t; i < ncached; i += 64) {   // same-lane RAW vs P1 writes
    float4 v = elds[i];
    float e0 = __expf(v.x - m0);
    float e1 = __expf(v.y - m1);
    float e2 = __expf(v.z - m2);
    elds[i] = make_float4(e0, e1, e2, 0.f);
    d0 += e0; d1 += e1; d2 += e2;
  }
  wave_sync();

  // P3a: lane t owns feature d=t; x read is one 256B coalesced line per atom.
  float a0 = 0.f, a1 = 0.f, a2 = 0.f;
  const float* __restrict__ xcol = atom_feas + (size_t)s0 * NFEA + t;
#pragma unroll 4
  for (int a = 0; a < ncached; ++a) {
    float xv = xcol[(size_t)a * NFEA];
    float4 e = elds[a];                      // same-address broadcast: conflict-free
    a0 = fmaf(xv, e.x, a0);
    a1 = fmaf(xv, e.y, a1);
    a2 = fmaf(xv, e.z, a2);
  }

  // P3b: overflow (n > LCAP), recompute e chunk-wise through own LDS slice.
  for (int c0 = LCAP; c0 < n; c0 += 64) {
    wave_sync();                             // prior reads retired before overwrite
    int i = c0 + t;
    bool act = i < n;
    int aa = s0 + (act ? i : (n - 1));
    float lg[3];
    mlp_logits(atom_feas + (size_t)aa * NFEA, W1, b1, W2, b2, lg);
    float e0 = act ? __expf(lg[0] - m0) : 0.f;
    float e1 = act ? __expf(lg[1] - m1) : 0.f;
    float e2 = act ? __expf(lg[2] - m2) : 0.f;
    d0 += e0; d1 += e1; d2 += e2;
    elds[t] = make_float4(e0, e1, e2, 0.f);
    wave_sync();
    int cnt = n - c0; if (cnt > 64) cnt = 64;
    const float* xc2 = atom_feas + (size_t)(s0 + c0) * NFEA + t;
    for (int a = 0; a < cnt; ++a) {
      float xv = xc2[(size_t)a * NFEA];
      float4 e = elds[a];
      a0 = fmaf(xv, e.x, a0);
      a1 = fmaf(xv, e.y, a1);
      a2 = fmaf(xv, e.z, a2);
    }
  }

#pragma unroll
  for (int off = 32; off > 0; off >>= 1) {
    d0 += __shfl_xor(d0, off);
    d1 += __shfl_xor(d1, off);
    d2 += __shfl_xor(d2, off);
  }
  float i0 = 1.f / d0, i1 = 1.f / d1, i2 = 1.f / d2;  // denom >= 1 always
  outg[t * 3 + 0] = a0 * i0;
  outg[t * 3 + 1] = a1 * i1;
  outg[t * 3 + 2] = a2 * i2;
}

extern "C" void kernel_launch(void* const* d_in, const int* in_sizes, int n_in,
                              void* d_out, int out_size, void* d_ws, size_t ws_size,
                              hipStream_t stream)
{
  const float* atom_feas = (const float*)d_in[0];
  const int*   owner     = (const int*)d_in[1];
  const float* W1        = (const float*)d_in[2];
  const float* b1        = (const float*)d_in[3];
  const float* W2        = (const float*)d_in[4];
  const float* b2        = (const float*)d_in[5];
  float* out = (float*)d_out;

  const int n_atoms  = in_sizes[1];
  const int n_graphs = out_size / (NFEA * NHEAD);

  int* starts = (int*)d_ws;  // n_graphs+1 ints

  hipLaunchKernelGGL(gar_starts, dim3((n_atoms + 255) / 256), dim3(256), 0, stream,
                     owner, starts, n_atoms, n_graphs);
  hipLaunchKernelGGL(gar_main, dim3((n_graphs + GPB - 1) / GPB), dim3(GPB * 64), 0, stream,
                     atom_feas, starts, W1, b1, W2, b2, out, n_graphs);
}

// Round 3
// 465.450 us; speedup vs baseline: 1.2475x; 1.2475x over previous
//
#include <hip/hip_runtime.h>
#include <math.h>
#include <stdint.h>

#define NFEA  64
#define NHEAD 3
#define GPB   2     // waves (= graphs) per block
#define CH    64    // atoms per chunk (one per lane)

typedef float v2f __attribute__((ext_vector_type(2)));

// Wave-local ordering only — waves never share LDS here, no s_barrier needed.
__device__ __forceinline__ void wave_sync_lds() {
  asm volatile("s_waitcnt lgkmcnt(0)" ::: "memory");
}
__device__ __forceinline__ void wait_vm0() {
  asm volatile("s_waitcnt vmcnt(0)" ::: "memory");
}

// Segment starts from the sorted owner array.
__global__ void gar_starts(const int* __restrict__ owner, int* __restrict__ starts,
                           int n_atoms, int n_graphs)
{
  int a = blockIdx.x * blockDim.x + threadIdx.x;
  if (a >= n_atoms) return;
  int cur  = owner[a];
  int prev = (a == 0) ? -1 : owner[a - 1];
  for (int g = prev + 1; g <= cur; ++g) starts[g] = a;
  if (a == n_atoms - 1)
    for (int g = cur + 1; g <= n_graphs; ++g) starts[g] = n_atoms;
}

// One wave per graph, online-softmax over 64-atom chunks.
// Per chunk: global_load_lds-stage x (coalesced, swizzled source) -> MLP from
// LDS (lane=atom) -> shfl max/sum reduce + rescale -> pool from LDS
// (lane=feature, e broadcast via readlane). x is read from HBM exactly once.
__global__ __launch_bounds__(GPB * 64, 4) void gar_main(
    const float* __restrict__ atom_feas,
    const int*   __restrict__ starts,
    const float* __restrict__ W1, const float* __restrict__ b1,
    const float* __restrict__ W2, const float* __restrict__ b2,
    float* __restrict__ out, int n_graphs, int n_atoms)
{
  __shared__ __align__(16) float xl_all[GPB][CH * NFEA];  // 16 KB per wave
  const int w = threadIdx.x >> 6;
  const int t = threadIdx.x & 63;
  const int g = blockIdx.x * GPB + w;
  if (g >= n_graphs) return;
  float* xl = xl_all[w];

  const int s0 = starts[g];
  const int n  = starts[g + 1] - s0;
  float* __restrict__ outg = out + (size_t)g * (NFEA * NHEAD);
  if (n <= 0) {  // empty graph: segment_sum -> zeros
    outg[t * 3 + 0] = 0.f; outg[t * 3 + 1] = 0.f; outg[t * 3 + 2] = 0.f;
    return;
  }

  // Pre-swizzled per-lane source byte offsets (pattern repeats every 4 j's):
  // copy instr j, lane t: local row i = j*4 + t/16, slot s = (t&15)^(i&15);
  // source byte = i*256 + s*16; LDS dest is linear -> LDS[i][slot t&15].
  unsigned offp[4];
#pragma unroll
  for (int jm = 0; jm < 4; ++jm) {
    int i = jm * 4 + (t >> 4);
    int s = (t & 15) ^ (i & 15);
    offp[jm] = (unsigned)(i * 256 + s * 16);
  }
  const unsigned max_src = (unsigned)n_atoms * 256u - 16u;
  const char* __restrict__ xbytes = (const char*)atom_feas;

  float m0 = -INFINITY, m1 = -INFINITY, m2 = -INFINITY;
  float d0 = 0.f, d1 = 0.f, d2 = 0.f;
  float a0 = 0.f, a1 = 0.f, a2 = 0.f;

  const int nc = (n + CH - 1) / CH;
  const int isw = (t & 15);        // MLP row-swizzle key (lane = local atom t)
  const int prow = (t >> 2) << 2;  // pool slot base
  const int pcol = (t & 3);        // pool dword-in-slot

  for (int c = 0; c < nc; ++c) {
    wave_sync_lds();  // pool ds_reads of prev chunk retired before LDS overwrite
    const unsigned cbase = (unsigned)(s0 + c * CH) * 256u;
#pragma unroll
    for (int j = 0; j < 16; ++j) {
      unsigned src = cbase + offp[j & 3] + (unsigned)((j >> 2) * 4096);
      if (src > max_src) src = max_src;  // clamp: garbage rows are masked later
      __builtin_amdgcn_global_load_lds(
          (const __attribute__((address_space(1))) void*)(xbytes + src),
          (__attribute__((address_space(3))) void*)(xl + j * 256),
          16, 0, 0);
    }
    wait_vm0();  // all 16 KB landed in LDS

    // ---- MLP: lane = local atom t, x row from LDS (swizzled b128 reads) ----
    v2f h[16];
#pragma unroll
    for (int j = 0; j < 16; ++j) h[j] = ((const v2f*)b1)[j];
    const int ibase = t * 64;
#pragma unroll
    for (int q = 0; q < 16; ++q) {
      float4 xq = *(const float4*)(xl + ibase + ((q ^ isw) << 2));
      float xs[4] = {xq.x, xq.y, xq.z, xq.w};
#pragma unroll
      for (int dd = 0; dd < 4; ++dd) {
        v2f xd2 = {xs[dd], xs[dd]};
        const v2f* wrow = ((const v2f*)W1) + (q * 4 + dd) * 16;
#pragma unroll
        for (int jj = 0; jj < 16; ++jj)
          h[jj] = __builtin_elementwise_fma(xd2, wrow[jj], h[jj]);
      }
    }
    float l0 = b2[0], l1 = b2[1], l2 = b2[2];
#pragma unroll
    for (int jj = 0; jj < 16; ++jj) {
#pragma unroll
      for (int cc = 0; cc < 2; ++cc) {
        float hj = h[jj][cc];
        float s = hj * __builtin_amdgcn_rcpf(1.0f + __expf(-hj));  // SiLU
        int k = 2 * jj + cc;
        l0 = fmaf(s, W2[k * 3 + 0], l0);
        l1 = fmaf(s, W2[k * 3 + 1], l1);
        l2 = fmaf(s, W2[k * 3 + 2], l2);
      }
    }
    const bool act = (c * CH + t) < n;
    if (!act) { l0 = -INFINITY; l1 = -INFINITY; l2 = -INFINITY; }

    // ---- chunk max (shfl tree), online rescale ----
    float c0 = l0, c1 = l1, c2 = l2;
#pragma unroll
    for (int off = 32; off > 0; off >>= 1) {
      c0 = fmaxf(c0, __shfl_xor(c0, off));
      c1 = fmaxf(c1, __shfl_xor(c1, off));
      c2 = fmaxf(c2, __shfl_xor(c2, off));
    }
    const float n0 = fmaxf(m0, c0), n1 = fmaxf(m1, c1), n2 = fmaxf(m2, c2);
    const float r0 = __expf(m0 - n0), r1 = __expf(m1 - n1), r2 = __expf(m2 - n2);
    m0 = n0; m1 = n1; m2 = n2;

    const float e0 = __expf(l0 - n0);  // -inf -> 0 for inactive lanes
    const float e1 = __expf(l1 - n1);
    const float e2 = __expf(l2 - n2);
    float s0s = e0, s1s = e1, s2s = e2;
#pragma unroll
    for (int off = 32; off > 0; off >>= 1) {
      s0s += __shfl_xor(s0s, off);
      s1s += __shfl_xor(s1s, off);
      s2s += __shfl_xor(s2s, off);
    }
    d0 = d0 * r0 + s0s;
    d1 = d1 * r1 + s1s;
    d2 = d2 * r2 + s2s;

    // ---- pool: lane = feature t; x from LDS, e broadcast via readlane ----
    a0 *= r0; a1 *= r1; a2 *= r2;
    int cnt = n - c * CH; if (cnt > CH) cnt = CH;
#pragma unroll 4
    for (int a = 0; a < cnt; ++a) {
      float xv = xl[a * 64 + (prow ^ ((a & 15) << 2)) + pcol];
      float ea0 = __shfl(e0, a);
      float ea1 = __shfl(e1, a);
      float ea2 = __shfl(e2, a);
      a0 = fmaf(ea0, xv, a0);
      a1 = fmaf(ea1, xv, a1);
      a2 = fmaf(ea2, xv, a2);
    }
  }

  const float i0 = 1.f / d0, i1 = 1.f / d1, i2 = 1.f / d2;  // d >= 1 always
  outg[t * 3 + 0] = a0 * i0;
  outg[t * 3 + 1] = a1 * i1;
  outg[t * 3 + 2] = a2 * i2;
}

extern "C" void kernel_launch(void* const* d_in, const int* in_sizes, int n_in,
                              void* d_out, int out_size, void* d_ws, size_t ws_size,
                              hipStream_t stream)
{
  const float* atom_feas = (const float*)d_in[0];
  const int*   owner     = (const int*)d_in[1];
  const float* W1        = (const float*)d_in[2];
  const float* b1        = (const float*)d_in[3];
  const float* W2        = (const float*)d_in[4];
  const float* b2        = (const float*)d_in[5];
  float* out = (float*)d_out;

  const int n_atoms  = in_sizes[1];
  const int n_graphs = out_size / (NFEA * NHEAD);

  int* starts = (int*)d_ws;  // n_graphs+1 ints

  hipLaunchKernelGGL(gar_starts, dim3((n_atoms + 255) / 256), dim3(256), 0, stream,
                     owner, starts, n_atoms, n_graphs);
  hipLaunchKernelGGL(gar_main, dim3((n_graphs + GPB - 1) / GPB), dim3(GPB * 64), 0, stream,
                     atom_feas, starts, W1, b1, W2, b2, out, n_graphs, n_atoms);
}